// Round 1
// 219.756 us; speedup vs baseline: 1.4016x; 1.4016x over previous
//
#include <hip/hip_runtime.h>

typedef unsigned short u16;
typedef unsigned int   u32;
typedef __bf16 bf16x8 __attribute__((ext_vector_type(8)));
typedef float  f32x4  __attribute__((ext_vector_type(4)));
typedef u32    u32x4  __attribute__((ext_vector_type(4)));
typedef u16    u16x4  __attribute__((ext_vector_type(4)));
typedef u16    u16x8v __attribute__((ext_vector_type(8)));

#define R_DIM 400
#define F_DIM 256
#define M_TOT 51200
#define INVALID 0xFFFFFFFFu

__device__ __forceinline__ u16 f2bf(float f) {
    union { float f; u32 i; } x; x.f = f;
    u32 r = x.i + 0x7FFFu + ((x.i >> 16) & 1u);   // RNE
    return (u16)(r >> 16);
}

// ---------------------------------------------------------------------------
// Kernel 1: convert fp32 W -> bf16 B-fragments (unchanged, verified).
// Fragment g = (ks 0..7, T 0..15, L 0..63):
//   Wf[g][0..7] = bf16( W[T*16 + (L&15)][ks*32 + (L>>4)*8 .. +7] )
// ---------------------------------------------------------------------------
__global__ __launch_bounds__(256) void wprep_f32(const float* __restrict__ W,
                                                 u16* __restrict__ Wf) {
    int g  = blockIdx.x * 256 + threadIdx.x;   // 0..8191
    int ks = g >> 10;
    int T  = (g >> 6) & 15;
    int L  = g & 63;
    int n  = T * 16 + (L & 15);
    int k  = ks * 32 + (L >> 4) * 8;
    const float* wp = W + (size_t)n * F_DIM + k;
    float4 lo = *(const float4*)wp;
    float4 hi = *(const float4*)(wp + 4);
    u16x8v t;
    t[0] = f2bf(lo.x); t[1] = f2bf(lo.y); t[2] = f2bf(lo.z); t[3] = f2bf(lo.w);
    t[4] = f2bf(hi.x); t[5] = f2bf(hi.y); t[6] = f2bf(hi.z); t[7] = f2bf(hi.w);
    *(u16x8v*)(Wf + (size_t)g * 8) = t;
}

// ---------------------------------------------------------------------------
// Kernel 2: FULLY FUSED  ranks + gather + MFMA GEMM + epilogue.
// 32 rows/block, 1600 blocks, XCD-contiguous block swizzle.
//  Phase A (per wave, 8 rows): read full A row (float4), extract the 6 ref
//    values (cols 0,8..12) via __shfl from the loaded row, count-based rank
//    (verified formula), packed 2x3x10-bit butterfly reduce -> slot list in LDS.
//  Phase B (per wave, same 8 rows): branch-free gather — all 7 weight loads
//    (A, L2-hot) + 7 feats float4 loads issued back-to-back; invalid slot =
//    pos 0 with weight 0 (same summation order for valid slots as before).
//  Phase C: probe-decoded MFMA K-loop + relu/bias/residual epilogue
//    (identical logic to the verified kernel, M-tile 64 -> 32).
// ---------------------------------------------------------------------------
__global__ __launch_bounds__(256) void gcn_fused(const float* __restrict__ A,
                                                 const float* __restrict__ feats,
                                                 const u16*  __restrict__ Wf,
                                                 const float* __restrict__ bias,
                                                 float* __restrict__ out) {
    __shared__ __align__(16) u16 agg_lds[32][264];   // bf16 agg tile (+pad: 2-way=free)
    __shared__ __align__(16) u32 slot_lds[32][8];    // gather positions per row
    __shared__ __align__(16) u16 probeA[16][32];
    __shared__ __align__(16) u16 probeB[16][32];

    const int tid = threadIdx.x, wid = tid >> 6, lane = tid & 63;
    // XCD swizzle: XCD x (= bid&7) owns contiguous rows [x*6400, (x+1)*6400)
    const int bid = (int)blockIdx.x;
    const int m0  = ((bid & 7) * 200 + (bid >> 3)) * 32;
    const int kg  = (lane >> 4) << 3;

    // probe tiles: A[m][0]=m, A[m][1]=1; B[n][0]=16, B[n][1]=n  -> D=16m+n
    for (int e = tid; e < 512; e += 256) {
        int r = e >> 5, k = e & 31;
        probeA[r][k] = (k == 0) ? f2bf((float)r) : ((k == 1) ? f2bf(1.0f) : (u16)0);
        probeB[r][k] = (k == 0) ? f2bf(16.0f)    : ((k == 1) ? f2bf((float)r) : (u16)0);
    }

    const int rbase = wid * 8;   // this wave's 8 rows: rbase..rbase+7

    // ---- phase A: ranks of cols {0,8..12} for this wave's rows ----
#pragma unroll 2
    for (int rr = 0; rr < 8; rr++) {
        const int r   = rbase + rr;
        const int row = m0 + r;
        const float* Ar = A + (size_t)row * R_DIM;

        float4 v0 = *(const float4*)(Ar + lane * 4);                       // cols 0..255
        float4 v1 = *(const float4*)(Ar + (lane < 36 ? 256 + lane * 4 : 0)); // cols 256..399
        if (lane >= 36) { v1.x = -1.0f; v1.y = -1.0f; v1.z = -1.0f; v1.w = -1.0f; } // A in [0,1): never counts

        // ref values from the loaded row (col0 -> lane0.x; 8..11 -> lane2; 12 -> lane3.x)
        float refs[6];
        refs[0] = __shfl(v0.x, 0);
        refs[1] = __shfl(v0.x, 2);
        refs[2] = __shfl(v0.y, 2);
        refs[3] = __shfl(v0.z, 2);
        refs[4] = __shfl(v0.w, 2);
        refs[5] = __shfl(v0.x, 3);
        const int cols[6] = {0, 8, 9, 10, 11, 12};

        int c[6] = {0, 0, 0, 0, 0, 0};
        float e0[4] = {v0.x, v0.y, v0.z, v0.w};
        float e1[4] = {v1.x, v1.y, v1.z, v1.w};
#pragma unroll
        for (int jj = 0; jj < 4; jj++) {
            float a = e0[jj]; int j = (lane << 2) + jj;
#pragma unroll
            for (int k = 0; k < 6; k++)
                c[k] += (a > refs[k] || (a == refs[k] && j < cols[k])) ? 1 : 0;
        }
#pragma unroll
        for (int jj = 0; jj < 4; jj++) {
            float a = e1[jj]; int j = 256 + (lane << 2) + jj;
#pragma unroll
            for (int k = 0; k < 6; k++)
                c[k] += (a > refs[k] || (a == refs[k] && j < cols[k])) ? 1 : 0;
        }
        u32 p0 = (u32)c[0] | ((u32)c[1] << 10) | ((u32)c[2] << 20);
        u32 p1 = (u32)c[3] | ((u32)c[4] << 10) | ((u32)c[5] << 20);
#pragma unroll
        for (int off = 32; off; off >>= 1) {
            p0 += __shfl_xor(p0, off);
            p1 += __shfl_xor(p1, off);
        }

        if (lane < 7) {
            u32 slot;
            if (lane < 6) {
                unsigned long long all = (((unsigned long long)p1) << 30) | (unsigned long long)p0;
                slot = (u32)((all >> (10 * lane)) & 1023u);
            } else {
                int i  = row % R_DIM;
                int q0 = p0 & 1023, q1 = (p0 >> 10) & 1023, q2 = (p0 >> 20) & 1023;
                int q3 = p1 & 1023, q4 = (p1 >> 10) & 1023, q5 = (p1 >> 20) & 1023;
                bool dup = (i == q0) | (i == q1) | (i == q2) | (i == q3) | (i == q4) | (i == q5);
                slot = dup ? INVALID : (u32)i;
            }
            slot_lds[r][lane] = slot;
        }
    }

    // ---- phase B: branch-free batched gather (no barrier: own-wave slots) ----
    for (int rr = 0; rr < 8; rr++) {
        const int r   = rbase + rr;
        const int row = m0 + r;
        const int bh  = row / R_DIM;
        const float* Ar = A + (size_t)row * R_DIM;
        const float* fb = feats + (size_t)bh * R_DIM * F_DIM + lane * 4;

        u32 e[7];
#pragma unroll
        for (int s = 0; s < 7; s++) e[s] = slot_lds[r][s];

        float w[7]; float4 f[7];
#pragma unroll
        for (int s = 0; s < 7; s++) {
            u32 es = (e[s] == INVALID) ? 0u : e[s];
            w[s] = Ar[es];                                   // L2-hot scalar
            f[s] = *(const float4*)(fb + (size_t)es * F_DIM); // coalesced 1KB/row
        }
        float a0 = 0.f, a1 = 0.f, a2 = 0.f, a3 = 0.f;
#pragma unroll
        for (int s = 0; s < 7; s++) {
            float ws = (e[s] == INVALID) ? 0.f : w[s];
            a0 += ws * f[s].x; a1 += ws * f[s].y; a2 += ws * f[s].z; a3 += ws * f[s].w;
        }
        u16x4 st = { f2bf(a0), f2bf(a1), f2bf(a2), f2bf(a3) };
        *(u16x4*)&agg_lds[r][lane * 4] = st;
    }
    __syncthreads();

    // ---- probe MFMA: decode true per-register (row,col) ----
    int rowi[4], coli[4];
    {
        bf16x8 pa = *(const bf16x8*)&probeA[lane & 15][kg];
        bf16x8 pb = *(const bf16x8*)&probeB[lane & 15][kg];
        f32x4 pd = {0.f, 0.f, 0.f, 0.f};
        pd = __builtin_amdgcn_mfma_f32_16x16x32_bf16(pa, pb, pd, 0, 0, 0);
#pragma unroll
        for (int reg = 0; reg < 4; reg++) {
            int v = (int)(pd[reg] + 0.5f);
            rowi[reg] = v >> 4;
            coli[reg] = v & 15;
        }
    }

    // ---- phase C: MFMA K-loop (Wf frags direct from global, L2-hot) ----
    f32x4 acc[2][4];
#pragma unroll
    for (int mt = 0; mt < 2; mt++)
#pragma unroll
        for (int nt = 0; nt < 4; nt++)
            acc[mt][nt] = (f32x4){0.f, 0.f, 0.f, 0.f};

    for (int ks = 0; ks < 8; ks++) {
        bf16x8 af[2], bfr[4];
#pragma unroll
        for (int mt = 0; mt < 2; mt++)
            af[mt] = *(const bf16x8*)&agg_lds[mt * 16 + (lane & 15)][ks * 32 + kg];
#pragma unroll
        for (int nt = 0; nt < 4; nt++) {
            int T = wid * 4 + nt;             // wave w owns n-tiles 4w..4w+3
            u32x4 v = *(const u32x4*)(Wf + ((size_t)(ks * 16 + T) * 64 + lane) * 8);
            bfr[nt] = __builtin_bit_cast(bf16x8, v);
        }
#pragma unroll
        for (int mt = 0; mt < 2; mt++)
#pragma unroll
            for (int nt = 0; nt < 4; nt++)
                acc[mt][nt] = __builtin_amdgcn_mfma_f32_16x16x32_bf16(
                    af[mt], bfr[nt], acc[mt][nt], 0, 0, 0);
    }

    // ---- epilogue: relu(acc + b) + feats -> out (fp32) ----
#pragma unroll
    for (int nt = 0; nt < 4; nt++) {
        int nb = wid * 64 + nt * 16;
#pragma unroll
        for (int reg = 0; reg < 4; reg++) {
            int gn = nb + coli[reg];
            float bn = bias[gn];
#pragma unroll
            for (int mt = 0; mt < 2; mt++) {
                int gm = m0 + mt * 16 + rowi[reg];
                size_t off = (size_t)gm * F_DIM + gn;
                out[off] = fmaxf(acc[mt][nt][reg] + bn, 0.f) + feats[off];
            }
        }
    }
}

extern "C" void kernel_launch(void* const* d_in, const int* in_sizes, int n_in,
                              void* d_out, int out_size, void* d_ws, size_t ws_size,
                              hipStream_t stream) {
    const float* A     = (const float*)d_in[0];   // [16,8,400,400] fp32
    const float* feats = (const float*)d_in[1];   // [16,8,400,256] fp32
    const float* W     = (const float*)d_in[2];   // [256,256] fp32
    const float* bias  = (const float*)d_in[3];   // [256] fp32
    float* out = (float*)d_out;                   // [16,8,400,256] fp32

    u16* Wf = (u16*)d_ws;                         // 128 KB

    wprep_f32<<<32, 256, 0, stream>>>(W, Wf);
    gcn_fused<<<M_TOT / 32, 256, 0, stream>>>(A, feats, Wf, bias, out);
}

// Round 2
// 215.261 us; speedup vs baseline: 1.4309x; 1.0209x over previous
//
#include <hip/hip_runtime.h>

typedef unsigned short u16;
typedef unsigned int   u32;
typedef unsigned long long u64;
typedef __bf16 bf16x8 __attribute__((ext_vector_type(8)));
typedef float  f32x4  __attribute__((ext_vector_type(4)));
typedef u32    u32x4  __attribute__((ext_vector_type(4)));
typedef u16    u16x4  __attribute__((ext_vector_type(4)));
typedef u16    u16x8v __attribute__((ext_vector_type(8)));

#define R_DIM 400
#define F_DIM 256
#define M_TOT 51200

__device__ __forceinline__ u16 f2bf(float f) {
    union { float f; u32 i; } x; x.f = f;
    u32 r = x.i + 0x7FFFu + ((x.i >> 16) & 1u);   // RNE
    return (u16)(r >> 16);
}

// ---------------------------------------------------------------------------
// Kernel 1: convert fp32 W -> bf16 B-fragments (unchanged, verified).
// Fragment g = (ks 0..7, T 0..15, L 0..63):
//   Wf[g][0..7] = bf16( W[T*16 + (L&15)][ks*32 + (L>>4)*8 .. +7] )
// ---------------------------------------------------------------------------
__global__ __launch_bounds__(256) void wprep_f32(const float* __restrict__ W,
                                                 u16* __restrict__ Wf) {
    int g  = blockIdx.x * 256 + threadIdx.x;   // 0..8191
    int ks = g >> 10;
    int T  = (g >> 6) & 15;
    int L  = g & 63;
    int n  = T * 16 + (L & 15);
    int k  = ks * 32 + (L >> 4) * 8;
    const float* wp = W + (size_t)n * F_DIM + k;
    float4 lo = *(const float4*)wp;
    float4 hi = *(const float4*)(wp + 4);
    u16x8v t;
    t[0] = f2bf(lo.x); t[1] = f2bf(lo.y); t[2] = f2bf(lo.z); t[3] = f2bf(lo.w);
    t[4] = f2bf(hi.x); t[5] = f2bf(hi.y); t[6] = f2bf(hi.z); t[7] = f2bf(hi.w);
    *(u16x8v*)(Wf + (size_t)g * 8) = t;
}

// ---------------------------------------------------------------------------
// Ballot-based ranks: rank(c) = #{j: A[j]>A[c]} + #{j<c: A[j]==A[c]}.
// Counts are wave-uniform -> __ballot + popcount (scalar pipe), no butterfly.
// Slots: es[0..5]=ranks (always valid), es[6]=diag i, dup -> weight 0.
// ---------------------------------------------------------------------------
__device__ __forceinline__ void compute_slots(float4 v0, float4 v1r, int lane,
                                              int row, u32 es[7], u32* dup_out) {
    float4 v1 = v1r;
    if (lane >= 36) { v1.x = -1.f; v1.y = -1.f; v1.z = -1.f; v1.w = -1.f; } // A in [0,1): never counts
    float refs[6];
    refs[0] = __shfl(v0.x, 0);   // col 0
    refs[1] = __shfl(v0.x, 2);   // col 8
    refs[2] = __shfl(v0.y, 2);   // col 9
    refs[3] = __shfl(v0.z, 2);   // col 10
    refs[4] = __shfl(v0.w, 2);   // col 11
    refs[5] = __shfl(v0.x, 3);   // col 12
    const int cols[6] = {0, 8, 9, 10, 11, 12};
    float e0[4] = {v0.x, v0.y, v0.z, v0.w};
    float e1[4] = {v1.x, v1.y, v1.z, v1.w};
    u32 cnt[6];
#pragma unroll
    for (int k = 0; k < 6; k++) {
        int c = 0;
#pragma unroll
        for (int jj = 0; jj < 4; jj++) {
            int j = (lane << 2) + jj;
            c += __popcll(__ballot(e0[jj] > refs[k] ||
                                   (e0[jj] == refs[k] && j < cols[k])));
            c += __popcll(__ballot(e1[jj] > refs[k]));   // j>=256 > cols[k] always
        }
        cnt[k] = (u32)c;
    }
    int i = row % R_DIM;
    bool dup = (i == (int)cnt[0]) | (i == (int)cnt[1]) | (i == (int)cnt[2]) |
               (i == (int)cnt[3]) | (i == (int)cnt[4]) | (i == (int)cnt[5]);
#pragma unroll
    for (int s = 0; s < 6; s++) es[s] = cnt[s];
    es[6] = (u32)i;
    *dup_out = dup ? 1u : 0u;
}

// ---------------------------------------------------------------------------
// Kernel 2: FULLY FUSED, software-pipelined.
// Per wave (8 rows): pipeline {prefetch A-row rr+1, ballot-ranks rr,
// issue 14 gather loads rr, consume gather rr-1 (FMA + bf16 LDS store)}.
// Gather latency hides under next row's rank compute; no slot round-trip.
// Then probe-decoded MFMA K-loop + relu/bias/residual epilogue (verified).
// ---------------------------------------------------------------------------
__global__ __launch_bounds__(256) void gcn_fused(const float* __restrict__ A,
                                                 const float* __restrict__ feats,
                                                 const u16*  __restrict__ Wf,
                                                 const float* __restrict__ bias,
                                                 float* __restrict__ out) {
    __shared__ __align__(16) u16 agg_lds[32][264];   // bf16 agg tile
    __shared__ __align__(16) u16 probeA[16][32];
    __shared__ __align__(16) u16 probeB[16][32];

    const int tid = threadIdx.x, wid = tid >> 6, lane = tid & 63;
    // XCD swizzle: XCD x (= bid&7) owns contiguous rows [x*6400, (x+1)*6400)
    const int bid = (int)blockIdx.x;
    const int m0  = ((bid & 7) * 200 + (bid >> 3)) * 32;
    const int kg  = (lane >> 4) << 3;

    // probe tiles: A[m][0]=m, A[m][1]=1; B[n][0]=16, B[n][1]=n  -> D=16m+n
    for (int e = tid; e < 512; e += 256) {
        int r = e >> 5, k = e & 31;
        probeA[r][k] = (k == 0) ? f2bf((float)r) : ((k == 1) ? f2bf(1.0f) : (u16)0);
        probeB[r][k] = (k == 0) ? f2bf(16.0f)    : ((k == 1) ? f2bf((float)r) : (u16)0);
    }

    const int rbase = wid * 8;   // this wave's rows: rbase..rbase+7

    // ---- fused rank+gather pipeline over 8 rows ----
    {
        const float* Ar0 = A + (size_t)(m0 + rbase) * R_DIM;
        float4 pa0 = *(const float4*)(Ar0 + lane * 4);
        float4 pa1 = *(const float4*)(Ar0 + (lane < 36 ? 256 + lane * 4 : 0));

        float  w_p[7];
        float4 f_p[7];
        u32    dup_p = 0;

#pragma unroll
        for (int rr = 0; rr < 8; rr++) {
            const int r   = rbase + rr;
            const int row = m0 + r;
            float4 v0 = pa0, v1 = pa1;
            if (rr < 7) {                       // prefetch next A row
                const float* An = A + (size_t)(row + 1) * R_DIM;
                pa0 = *(const float4*)(An + lane * 4);
                pa1 = *(const float4*)(An + (lane < 36 ? 256 + lane * 4 : 0));
            }

            u32 es[7], dupm;
            compute_slots(v0, v1, lane, row, es, &dupm);

            const int bh = row / R_DIM;
            const float* Ar = A + (size_t)row * R_DIM;
            const float* fb = feats + (size_t)bh * R_DIM * F_DIM + lane * 4;

            float w[7]; float4 f[7];
#pragma unroll
            for (int s = 0; s < 7; s++) {
                u32 e = es[s];
                w[s] = Ar[e];                                    // L1/L2-hot
                f[s] = *(const float4*)(fb + (size_t)e * F_DIM); // coalesced 1KB/row
            }

            if (rr > 0) {                       // consume previous row's gather
                float a0 = 0.f, a1 = 0.f, a2 = 0.f, a3 = 0.f;
#pragma unroll
                for (int s = 0; s < 7; s++) {
                    float ws = (s == 6 && dup_p) ? 0.f : w_p[s];
                    a0 += ws * f_p[s].x; a1 += ws * f_p[s].y;
                    a2 += ws * f_p[s].z; a3 += ws * f_p[s].w;
                }
                u16x4 st = { f2bf(a0), f2bf(a1), f2bf(a2), f2bf(a3) };
                *(u16x4*)&agg_lds[r - 1][lane * 4] = st;
            }
#pragma unroll
            for (int s = 0; s < 7; s++) { w_p[s] = w[s]; f_p[s] = f[s]; }
            dup_p = dupm;
        }
        // drain: consume last row
        {
            float a0 = 0.f, a1 = 0.f, a2 = 0.f, a3 = 0.f;
#pragma unroll
            for (int s = 0; s < 7; s++) {
                float ws = (s == 6 && dup_p) ? 0.f : w_p[s];
                a0 += ws * f_p[s].x; a1 += ws * f_p[s].y;
                a2 += ws * f_p[s].z; a3 += ws * f_p[s].w;
            }
            u16x4 st = { f2bf(a0), f2bf(a1), f2bf(a2), f2bf(a3) };
            *(u16x4*)&agg_lds[rbase + 7][lane * 4] = st;
        }
    }
    __syncthreads();

    // ---- probe MFMA: decode true per-register (row,col) ----
    int rowi[4], coli[4];
    {
        bf16x8 pa = *(const bf16x8*)&probeA[lane & 15][kg];
        bf16x8 pb = *(const bf16x8*)&probeB[lane & 15][kg];
        f32x4 pd = {0.f, 0.f, 0.f, 0.f};
        pd = __builtin_amdgcn_mfma_f32_16x16x32_bf16(pa, pb, pd, 0, 0, 0);
#pragma unroll
        for (int reg = 0; reg < 4; reg++) {
            int v = (int)(pd[reg] + 0.5f);
            rowi[reg] = v >> 4;
            coli[reg] = v & 15;
        }
    }

    // ---- MFMA K-loop (Wf frags direct from global, L2-hot) ----
    f32x4 acc[2][4];
#pragma unroll
    for (int mt = 0; mt < 2; mt++)
#pragma unroll
        for (int nt = 0; nt < 4; nt++)
            acc[mt][nt] = (f32x4){0.f, 0.f, 0.f, 0.f};

    for (int ks = 0; ks < 8; ks++) {
        bf16x8 af[2], bfr[4];
#pragma unroll
        for (int mt = 0; mt < 2; mt++)
            af[mt] = *(const bf16x8*)&agg_lds[mt * 16 + (lane & 15)][ks * 32 + kg];
#pragma unroll
        for (int nt = 0; nt < 4; nt++) {
            int T = wid * 4 + nt;             // wave w owns n-tiles 4w..4w+3
            u32x4 v = *(const u32x4*)(Wf + ((size_t)(ks * 16 + T) * 64 + lane) * 8);
            bfr[nt] = __builtin_bit_cast(bf16x8, v);
        }
#pragma unroll
        for (int mt = 0; mt < 2; mt++)
#pragma unroll
            for (int nt = 0; nt < 4; nt++)
                acc[mt][nt] = __builtin_amdgcn_mfma_f32_16x16x32_bf16(
                    af[mt], bfr[nt], acc[mt][nt], 0, 0, 0);
    }

    // ---- epilogue: relu(acc + b) + feats -> out (fp32) ----
#pragma unroll
    for (int nt = 0; nt < 4; nt++) {
        int nb = wid * 64 + nt * 16;
#pragma unroll
        for (int reg = 0; reg < 4; reg++) {
            int gn = nb + coli[reg];
            float bn = bias[gn];
#pragma unroll
            for (int mt = 0; mt < 2; mt++) {
                int gm = m0 + mt * 16 + rowi[reg];
                size_t off = (size_t)gm * F_DIM + gn;
                out[off] = fmaxf(acc[mt][nt][reg] + bn, 0.f) + feats[off];
            }
        }
    }
}

extern "C" void kernel_launch(void* const* d_in, const int* in_sizes, int n_in,
                              void* d_out, int out_size, void* d_ws, size_t ws_size,
                              hipStream_t stream) {
    const float* A     = (const float*)d_in[0];   // [16,8,400,400] fp32
    const float* feats = (const float*)d_in[1];   // [16,8,400,256] fp32
    const float* W     = (const float*)d_in[2];   // [256,256] fp32
    const float* bias  = (const float*)d_in[3];   // [256] fp32
    float* out = (float*)d_out;                   // [16,8,400,256] fp32

    u16* Wf = (u16*)d_ws;                         // 128 KB

    wprep_f32<<<32, 256, 0, stream>>>(W, Wf);
    gcn_fused<<<M_TOT / 32, 256, 0, stream>>>(A, feats, Wf, bias, out);
}